// Round 4
// baseline (398.823 us; speedup 1.0000x reference)
//
#include <hip/hip_runtime.h>
#include <hip/hip_bf16.h>
#include <stdint.h>

typedef __bf16 bf16_t;
typedef __bf16 bf16x8 __attribute__((ext_vector_type(8)));
typedef __bf16 bf16x4 __attribute__((ext_vector_type(4)));
typedef float  f32x4  __attribute__((ext_vector_type(4)));

#if __has_builtin(__builtin_amdgcn_exp2f)
#define EXP2F __builtin_amdgcn_exp2f
#else
#define EXP2F exp2f
#endif

// ---- helpers ---------------------------------------------------------------

__device__ __forceinline__ void async_copy16(void* lds, const void* gptr) {
  __builtin_amdgcn_global_load_lds(
      (const __attribute__((address_space(1))) void*)gptr,
      (__attribute__((address_space(3))) void*)lds, 16, 0, 0);
}

__device__ __forceinline__ f32x4 splat4(float x) {
  f32x4 r; r[0] = x; r[1] = x; r[2] = x; r[3] = x; return r;
}
__device__ __forceinline__ f32x4 vmax4(f32x4 a, f32x4 b) {
  f32x4 r;
  r[0] = fmaxf(a[0], b[0]); r[1] = fmaxf(a[1], b[1]);
  r[2] = fmaxf(a[2], b[2]); r[3] = fmaxf(a[3], b[3]);
  return r;
}

// ---- runtime dtype detection ------------------------------------------------
// fp32 buffers read as uint16 pairs: even (low) halves are mantissa garbage
// (uniform exponent field) or exactly 0 for constants like 1.0f; bf16 buffers
// have sane exponents everywhere.
__device__ __forceinline__ bool detect_fp32(const void* p) {
  const uint16_t* h = (const uint16_t*)p;
  int weird_even = 0, zero_even = 0, nz_odd = 0;
  for (int i = 0; i < 32; ++i) {
    uint16_t e = h[2 * i], o = h[2 * i + 1];
    int ee = (e >> 7) & 0xFF;
    if (e == 0) zero_even++;
    else if (ee < 90 || ee > 160) weird_even++;
    if (o != 0) nz_odd++;
  }
  return (weird_even >= 6) || (zero_even == 32 && nz_odd >= 1);
}

// ---- normalize all float inputs to canonical bf16 in ws ---------------------
__global__ __launch_bounds__(256) void convert_all(
    const void* s0, const void* s1, const void* s2, const void* s3,
    const void* s4, const void* s5, const void* s6, const void* s7,
    const void* s8, const void* s9, const void* s10, const void* s11,
    const void* s12, char* __restrict__ ws) {
  const void* srcs[13] = {s0, s1, s2, s3, s4, s5, s6, s7, s8, s9, s10, s11, s12};
  const int counts[13] = {4194304, 4194304, 4194304,          // Q K V
                          1048576, 1024, 1048576, 1024,       // wq bq wk bk
                          1048576, 1024, 1048576, 1024,       // wv bv wo bo
                          1024, 1024};                        // gamma beta
  const size_t dofs[13] = {
      0ull, 8ull << 20, 16ull << 20,
      24ull << 20, (32ull << 20) + 0 * 8192, 26ull << 20, (32ull << 20) + 1 * 8192,
      28ull << 20, (32ull << 20) + 2 * 8192, 30ull << 20, (32ull << 20) + 3 * 8192,
      (32ull << 20) + 4 * 8192, (32ull << 20) + 5 * 8192};
  const int bi = blockIdx.y;
  const void* src = srcs[bi];
  bf16x8* dst = (bf16x8*)(ws + dofs[bi]);
  const int nv = counts[bi] >> 3;
  const bool f32 = detect_fp32(src);
  const int idx = blockIdx.x * 256 + threadIdx.x;
  const int stride = gridDim.x * 256;
  if (f32) {
    const float4* s4p = (const float4*)src;
    for (int i = idx; i < nv; i += stride) {
      float4 a = s4p[2 * i], b = s4p[2 * i + 1];
      bf16x8 o;
      o[0] = (bf16_t)a.x; o[1] = (bf16_t)a.y; o[2] = (bf16_t)a.z; o[3] = (bf16_t)a.w;
      o[4] = (bf16_t)b.x; o[5] = (bf16_t)b.y; o[6] = (bf16_t)b.z; o[7] = (bf16_t)b.w;
      dst[i] = o;
    }
  } else {
    const bf16x8* s8p = (const bf16x8*)src;
    for (int i = idx; i < nv; i += stride) dst[i] = s8p[i];
  }
}

// ---- mask transpose + bitpack ----------------------------------------------
// out: mTb[b][k] is 64 uint32 words; bit q%32 of word q/32 = mask(b,q,k).
// bit==1 => masked (drop). Runtime classification of the mask encoding.
__device__ __forceinline__ int detect_mask(const uint8_t* p) {
  const uint32_t* w = (const uint32_t*)p;
  bool i32 = true;
  for (int i = 0; i < 32; ++i) i32 &= (w[i] <= 1u);
  if (i32) return 0;                          // int32 0/1
  const uint16_t* hh = (const uint16_t*)p;
  bool evz = true, oddok = true, allbf = true, allf16 = true;
  for (int i = 0; i < 32; ++i) {
    uint16_t e = hh[2 * i], o = hh[2 * i + 1];
    evz &= (e == 0);
    oddok &= (o == 0 || o == 0x3F80);
    allbf &= (e == 0 || e == 0x3F80) && (o == 0 || o == 0x3F80);
    allf16 &= (e == 0 || e == 0x3C00) && (o == 0 || o == 0x3C00);
  }
  if (evz && oddok) return 1;                 // fp32 0.0/1.0
  if (allbf || allf16) return 2;              // 16-bit 0/1.0
  return 3;                                   // 1-byte bool
}

__global__ __launch_bounds__(256) void mask_pack(const uint8_t* __restrict__ mraw,
                                                 uint8_t* __restrict__ outp) {
  const int mode = detect_mask(mraw);
  const int t = threadIdx.x;
  const int b = blockIdx.z, q0 = blockIdx.y * 32, k0 = blockIdx.x * 256;
  const int k = k0 + t;
  uint32_t bits = 0u;
  for (int r = 0; r < 32; ++r) {
    size_t idx = ((size_t)(b * 2048 + q0 + r)) * 2048 + k;
    bool mv;
    if (mode == 0)      mv = ((const int*)mraw)[idx] != 0;
    else if (mode == 1) mv = ((const uint32_t*)mraw)[idx] != 0u;
    else if (mode == 2) mv = ((const uint16_t*)mraw)[idx] != 0;
    else                mv = mraw[idx] != 0;
    bits |= (mv ? 1u : 0u) << r;
  }
  ((uint32_t*)outp)[(size_t)(b * 2048 + k) * 64 + (q0 >> 5)] = bits;
}

// ---- GEMM core: Y(128x128 tile) = X(4096x1024) * W(1024x1024)^T + bias -----
// MODE 0: plain bf16 row-major out
// MODE 1: V-projection: write transposed vT[((b*16+h)*64+d)*2048 + s] (bf16)
// MODE 2: out-projection: out = acc + bias + Qres, FLOAT32 row-major out
template <int MODE>
__device__ __forceinline__ void gemm_tile(const bf16_t* __restrict__ X,
                                          const bf16_t* __restrict__ W,
                                          const bf16_t* __restrict__ bias,
                                          const bf16_t* __restrict__ QresB,
                                          const float* __restrict__ QresF,
                                          bool qres_is_f32,
                                          void* __restrict__ outv) {
  __shared__ __align__(16) bf16_t sA[128 * 32];
  __shared__ __align__(16) bf16_t sB[128 * 32];
  const int tm = blockIdx.x * 128;
  const int tn = blockIdx.y * 128;
  const int t = threadIdx.x;
  const int w = t >> 6, l = t & 63, lc = l & 15, ql = l >> 4;
  const int wm = (w >> 1) * 64, wn = (w & 1) * 64;
  f32x4 acc[4][4];
  for (int i = 0; i < 4; ++i)
    for (int j = 0; j < 4; ++j) acc[i][j] = splat4(0.0f);

  const int m0 = t >> 2;          // chunk row
  const int kc0 = (t & 3) * 8;    // chunk k offset (elements)

  for (int k0 = 0; k0 < 1024; k0 += 32) {
    __syncthreads();  // previous tile fully consumed
    async_copy16((char*)sA + w * 1024,        X + (size_t)(tm + m0) * 1024 + k0 + kc0);
    async_copy16((char*)sA + 4096 + w * 1024, X + (size_t)(tm + 64 + m0) * 1024 + k0 + kc0);
    async_copy16((char*)sB + w * 1024,        W + (size_t)(tn + m0) * 1024 + k0 + kc0);
    async_copy16((char*)sB + 4096 + w * 1024, W + (size_t)(tn + 64 + m0) * 1024 + k0 + kc0);
    __syncthreads();  // drains vmcnt: staging visible

    bf16x8 af[4], bfr[4];
    for (int i = 0; i < 4; ++i)
      af[i] = *(const bf16x8*)(sA + (wm + i * 16 + lc) * 32 + ql * 8);
    for (int j = 0; j < 4; ++j)
      bfr[j] = *(const bf16x8*)(sB + (wn + j * 16 + lc) * 32 + ql * 8);
    for (int i = 0; i < 4; ++i)
      for (int j = 0; j < 4; ++j)
        acc[i][j] = __builtin_amdgcn_mfma_f32_16x16x32_bf16(af[i], bfr[j], acc[i][j], 0, 0, 0);
  }

  // epilogue.  C/D layout: row = (lane>>4)*4 + reg, col = lane&15.
  float bvals[4];
  for (int j = 0; j < 4; ++j) bvals[j] = (float)bias[tn + wn + j * 16 + lc];
  for (int i = 0; i < 4; ++i) {
    for (int j = 0; j < 4; ++j) {
      const int col = tn + wn + j * 16 + lc;
      for (int v = 0; v < 4; ++v) {
        const int row = tm + wm + i * 16 + ql * 4 + v;
        float val = acc[i][j][v] + bvals[j];
        if (MODE == 0) {
          ((bf16_t*)outv)[(size_t)row * 1024 + col] = (bf16_t)val;
        } else if (MODE == 1) {
          const int b = row >> 11;
          const int x = (row & 2047) * 1024 + col;  // flat (s*D + c) within batch
          const int h = x >> 17;
          const int s = (x >> 6) & 2047;
          const int d = x & 63;
          ((bf16_t*)outv)[(size_t)((b * 16 + h) * 64 + d) * 2048 + s] = (bf16_t)val;
        } else {
          val += qres_is_f32 ? QresF[(size_t)row * 1024 + col]
                             : (float)QresB[(size_t)row * 1024 + col];
          ((float*)outv)[(size_t)row * 1024 + col] = val;  // fp32 output
        }
      }
    }
  }
}

__global__ __launch_bounds__(256, 2) void qkv_gemm(
    const bf16_t* __restrict__ Q, const bf16_t* __restrict__ K, const bf16_t* __restrict__ V,
    const bf16_t* __restrict__ wq, const bf16_t* __restrict__ bq,
    const bf16_t* __restrict__ wk, const bf16_t* __restrict__ bk,
    const bf16_t* __restrict__ wv, const bf16_t* __restrict__ bv,
    bf16_t* __restrict__ qlin, bf16_t* __restrict__ klin, bf16_t* __restrict__ vT) {
  if (blockIdx.z == 0)      gemm_tile<0>(Q, wq, bq, nullptr, nullptr, false, qlin);
  else if (blockIdx.z == 1) gemm_tile<0>(K, wk, bk, nullptr, nullptr, false, klin);
  else                      gemm_tile<1>(V, wv, bv, nullptr, nullptr, false, vT);
}

__global__ __launch_bounds__(256, 2) void final_gemm(
    const bf16_t* __restrict__ ctx, const bf16_t* __restrict__ wo,
    const bf16_t* __restrict__ bo, const bf16_t* __restrict__ QresB,
    const void* __restrict__ Qraw, float* __restrict__ xres) {
  const bool qf32 = detect_fp32(Qraw);
  gemm_tile<2>(ctx, wo, bo, QresB, (const float*)Qraw, qf32, xres);
}

// ---- flash attention -------------------------------------------------------
__global__ __launch_bounds__(256, 2) void attn(const bf16_t* __restrict__ qlin,
                                               const bf16_t* __restrict__ klin,
                                               const bf16_t* __restrict__ vT,
                                               const uint8_t* __restrict__ mTb,
                                               bf16_t* __restrict__ ctx) {
  __shared__ __align__(16) bf16_t sK[128 * 64];    // [key][dk]   16 KB
  __shared__ __align__(16) bf16_t sVt[64 * 128];   // [dv][key]   16 KB
  __shared__ __align__(16) bf16_t sP[128 * 128];   // [qrow][key] 32 KB
  __shared__ __align__(16) uint8_t sM[128 * 16];   // [key][q bits/8]

  const int t = threadIdx.x, w = t >> 6, l = t & 63, lc = l & 15, ql = l >> 4;
  const int bid = blockIdx.x;
  const int qt = bid & 15, h = (bid >> 4) & 15, b = bid >> 8;
  const int q0 = qt * 128, rb = w * 32;

  const bf16_t* qh = qlin + (size_t)(b * 16 + h) * 2048 * 64;
  const bf16_t* kh = klin + (size_t)(b * 16 + h) * 2048 * 64;
  const bf16_t* vh = vT   + (size_t)(b * 16 + h) * 64 * 2048;
  const uint8_t* mh = mTb + (size_t)b * 2048 * 256 + (q0 >> 3);

  // Q fragments (A-operand: m = lane&15, k = (lane>>4)*8 + j)
  bf16x8 qf[2][2];
  for (int i = 0; i < 2; ++i)
    for (int ks = 0; ks < 2; ++ks)
      qf[i][ks] = *(const bf16x8*)(qh + (size_t)(q0 + rb + i * 16 + lc) * 64 + ks * 32 + ql * 8);

  f32x4 m_st[2], l_st[2], oacc[2][4];
  for (int i = 0; i < 2; ++i) {
    m_st[i] = splat4(-3e38f);
    l_st[i] = splat4(0.0f);
    for (int n = 0; n < 4; ++n) oacc[i][n] = splat4(0.0f);
  }
  const float SCL = 0.18033688f;  // log2(e) / sqrt(64)

  for (int kt = 0; kt < 16; ++kt) {
    const int k0 = kt * 128;
    __syncthreads();  // all waves done reading previous tiles
    {
      const bf16_t* kt0 = kh + (size_t)k0 * 64;
      for (int is = 0; is < 4; ++is)
        async_copy16((char*)sK + is * 4096 + w * 1024, kt0 + (size_t)(is * 256 + t) * 8);
      for (int is = 0; is < 4; ++is) {
        const int c = is * 256 + t;
        async_copy16((char*)sVt + is * 4096 + w * 1024,
                     vh + (size_t)(c >> 4) * 2048 + k0 + (c & 15) * 8);
      }
      if (w < 2) async_copy16((char*)sM + w * 1024, mh + (size_t)(k0 + t) * 256);
    }
    __syncthreads();  // staging visible

    // ---- scores: S = Q K^T * scale   (C layout: row=ql*4+v, col=lc)
    f32x4 sc[2][8];
    for (int j = 0; j < 8; ++j) {
      bf16x8 b0 = *(const bf16x8*)(sK + (j * 16 + lc) * 64 + ql * 8);
      bf16x8 b1 = *(const bf16x8*)(sK + (j * 16 + lc) * 64 + 32 + ql * 8);
      for (int i = 0; i < 2; ++i) {
        f32x4 a = splat4(0.0f);
        a = __builtin_amdgcn_mfma_f32_16x16x32_bf16(qf[i][0], b0, a, 0, 0, 0);
        a = __builtin_amdgcn_mfma_f32_16x16x32_bf16(qf[i][1], b1, a, 0, 0, 0);
        sc[i][j] = a * SCL;
      }
    }

    // ---- online softmax (exp2 domain). Mask applied multiplicatively to P.
    for (int i = 0; i < 2; ++i) {
      f32x4 tmax = sc[i][0];
      for (int j = 1; j < 8; ++j) tmax = vmax4(tmax, sc[i][j]);
      for (int d = 1; d < 16; d <<= 1) {
        f32x4 o;
        for (int v = 0; v < 4; ++v) o[v] = __shfl_xor(tmax[v], d, 64);
        tmax = vmax4(tmax, o);
      }
      f32x4 mnew = vmax4(m_st[i], tmax);
      f32x4 alpha;
      for (int v = 0; v < 4; ++v) alpha[v] = EXP2F(m_st[i][v] - mnew[v]);
      m_st[i] = mnew;
      for (int n = 0; n < 4; ++n) oacc[i][n] *= alpha;

      const int bitbase = rb + i * 16 + ql * 4;
      const int wordoff = (bitbase >> 5) * 4;
      const int shift = bitbase & 31;
      f32x4 rsum = splat4(0.0f);
      for (int j = 0; j < 8; ++j) {
        const uint32_t mword = *(const uint32_t*)(sM + (j * 16 + lc) * 16 + wordoff);
        const uint32_t m4 = (mword >> shift) & 0xFu;
        f32x4 p;
        for (int v = 0; v < 4; ++v) {
          const float e = EXP2F(sc[i][j][v] - mnew[v]);
          p[v] = ((m4 >> v) & 1u) ? 0.0f : e;
        }
        rsum += p;
        for (int v = 0; v < 4; ++v)
          sP[(rb + i * 16 + ql * 4 + v) * 128 + j * 16 + lc] = (bf16_t)p[v];
      }
      for (int d = 1; d < 16; d <<= 1) {
        f32x4 o;
        for (int v = 0; v < 4; ++v) o[v] = __shfl_xor(rsum[v], d, 64);
        rsum += o;
      }
      l_st[i] = l_st[i] * alpha + rsum;
    }

    // ---- O += P V   (P rows are wave-private: no barrier needed)
    for (int kq = 0; kq < 4; ++kq) {
      bf16x8 pa[2], vb[4];
      for (int i = 0; i < 2; ++i)
        pa[i] = *(const bf16x8*)(sP + (rb + i * 16 + lc) * 128 + kq * 32 + ql * 8);
      for (int n = 0; n < 4; ++n)
        vb[n] = *(const bf16x8*)(sVt + (n * 16 + lc) * 128 + kq * 32 + ql * 8);
      for (int i = 0; i < 2; ++i)
        for (int n = 0; n < 4; ++n)
          oacc[i][n] = __builtin_amdgcn_mfma_f32_16x16x32_bf16(pa[i], vb[n], oacc[i][n], 0, 0, 0);
    }
  }

  // ---- normalize and store: ctx[b, s, h*64+dv]
  for (int i = 0; i < 2; ++i) {
    f32x4 inv;
    for (int v = 0; v < 4; ++v) inv[v] = 1.0f / l_st[i][v];
    for (int n = 0; n < 4; ++n) {
      f32x4 o = oacc[i][n] * inv;
      for (int v = 0; v < 4; ++v) {
        const int row = q0 + rb + i * 16 + ql * 4 + v;
        ctx[(size_t)(b * 2048 + row) * 1024 + h * 64 + n * 16 + lc] = (bf16_t)o[v];
      }
    }
  }
}

// ---- LayerNorm (fp32 in, fp32 out, in place on d_out) ----------------------
__global__ __launch_bounds__(256) void ln_k(float* __restrict__ x,
                                            const bf16_t* __restrict__ gamma,
                                            const bf16_t* __restrict__ beta) {
  const int row = blockIdx.x, t = threadIdx.x, w = t >> 6, l = t & 63;
  float* xr = x + (size_t)row * 1024;
  float4 xv = ((const float4*)xr)[t];
  float v0 = xv.x, v1 = xv.y, v2 = xv.z, v3 = xv.w;
  float s1 = v0 + v1 + v2 + v3;
  float s2 = v0 * v0 + v1 * v1 + v2 * v2 + v3 * v3;
  for (int d = 1; d < 64; d <<= 1) {
    s1 += __shfl_xor(s1, d, 64);
    s2 += __shfl_xor(s2, d, 64);
  }
  __shared__ float red[8];
  if (l == 0) { red[w] = s1; red[4 + w] = s2; }
  __syncthreads();
  s1 = red[0] + red[1] + red[2] + red[3];
  s2 = red[4] + red[5] + red[6] + red[7];
  const float mean = s1 * (1.0f / 1024.0f);
  const float var = s2 * (1.0f / 1024.0f) - mean * mean;
  const float rstd = rsqrtf(var + 1e-5f);
  bf16x4 gv = *(const bf16x4*)(gamma + t * 4);
  bf16x4 bv = *(const bf16x4*)(beta + t * 4);
  float4 ov;
  ov.x = (v0 - mean) * rstd * (float)gv[0] + (float)bv[0];
  ov.y = (v1 - mean) * rstd * (float)gv[1] + (float)bv[1];
  ov.z = (v2 - mean) * rstd * (float)gv[2] + (float)bv[2];
  ov.w = (v3 - mean) * rstd * (float)gv[3] + (float)bv[3];
  ((float4*)xr)[t] = ov;
}

// ---- launch ----------------------------------------------------------------
extern "C" void kernel_launch(void* const* d_in, const int* in_sizes, int n_in,
                              void* d_out, int out_size, void* d_ws, size_t ws_size,
                              hipStream_t stream) {
  const uint8_t* msk = (const uint8_t*)d_in[3];

  char* ws = (char*)d_ws;
  // canonical bf16 inputs
  bf16_t* Qc   = (bf16_t*)(ws + 0);
  bf16_t* Kc   = (bf16_t*)(ws + (8ull << 20));   // slot reused as ctx after qkv_gemm
  bf16_t* Vc   = (bf16_t*)(ws + (16ull << 20));
  bf16_t* wqc  = (bf16_t*)(ws + (24ull << 20));
  bf16_t* wkc  = (bf16_t*)(ws + (26ull << 20));
  bf16_t* wvc  = (bf16_t*)(ws + (28ull << 20));
  bf16_t* woc  = (bf16_t*)(ws + (30ull << 20));
  bf16_t* bqc  = (bf16_t*)(ws + (32ull << 20) + 0 * 8192);
  bf16_t* bkc  = (bf16_t*)(ws + (32ull << 20) + 1 * 8192);
  bf16_t* bvc  = (bf16_t*)(ws + (32ull << 20) + 2 * 8192);
  bf16_t* boc  = (bf16_t*)(ws + (32ull << 20) + 3 * 8192);
  bf16_t* gc   = (bf16_t*)(ws + (32ull << 20) + 4 * 8192);
  bf16_t* bec  = (bf16_t*)(ws + (32ull << 20) + 5 * 8192);
  // intermediates
  uint8_t* mTb = (uint8_t*)(ws + (33ull << 20));
  bf16_t* qlin = (bf16_t*)(ws + (34ull << 20));
  bf16_t* klin = (bf16_t*)(ws + (42ull << 20));
  bf16_t* vT   = (bf16_t*)(ws + (50ull << 20));
  bf16_t* ctx  = Kc;  // Kc dead after qkv_gemm
  float* outF  = (float*)d_out;

  convert_all<<<dim3(512, 13), 256, 0, stream>>>(
      d_in[0], d_in[1], d_in[2], d_in[4], d_in[5], d_in[6], d_in[7],
      d_in[8], d_in[9], d_in[10], d_in[11], d_in[12], d_in[13], ws);
  mask_pack<<<dim3(8, 64, 2), 256, 0, stream>>>(msk, mTb);
  qkv_gemm<<<dim3(32, 8, 3), 256, 0, stream>>>(Qc, Kc, Vc, wqc, bqc, wkc, bkc,
                                               wvc, bvc, qlin, klin, vT);
  attn<<<dim3(512), 256, 0, stream>>>(qlin, klin, vT, mTb, ctx);
  final_gemm<<<dim3(32, 8), 256, 0, stream>>>(ctx, woc, boc, Qc, d_in[0], outF);
  ln_k<<<dim3(4096), 256, 0, stream>>>(outF, gc, bec);
}

// Round 6
// 322.890 us; speedup vs baseline: 1.2352x; 1.2352x over previous
//
#include <hip/hip_runtime.h>
#include <hip/hip_bf16.h>
#include <stdint.h>

typedef __bf16 bf16_t;
typedef __bf16 bf16x8 __attribute__((ext_vector_type(8)));
typedef __bf16 bf16x4 __attribute__((ext_vector_type(4)));
typedef float  f32x4  __attribute__((ext_vector_type(4)));

#if __has_builtin(__builtin_amdgcn_exp2f)
#define EXP2F __builtin_amdgcn_exp2f
#else
#define EXP2F exp2f
#endif

// ---- helpers ---------------------------------------------------------------

__device__ __forceinline__ void async_copy16(void* lds, const void* gptr) {
  __builtin_amdgcn_global_load_lds(
      (const __attribute__((address_space(1))) void*)gptr,
      (__attribute__((address_space(3))) void*)lds, 16, 0, 0);
}

__device__ __forceinline__ f32x4 splat4(float x) {
  f32x4 r; r[0] = x; r[1] = x; r[2] = x; r[3] = x; return r;
}

// ---- runtime dtype detection ------------------------------------------------
__device__ __forceinline__ bool detect_fp32(const void* p) {
  const uint16_t* h = (const uint16_t*)p;
  int weird_even = 0, zero_even = 0, nz_odd = 0;
  for (int i = 0; i < 32; ++i) {
    uint16_t e = h[2 * i], o = h[2 * i + 1];
    int ee = (e >> 7) & 0xFF;
    if (e == 0) zero_even++;
    else if (ee < 90 || ee > 160) weird_even++;
    if (o != 0) nz_odd++;
  }
  return (weird_even >= 6) || (zero_even == 32 && nz_odd >= 1);
}

// ---- normalize all float inputs to canonical bf16 in ws ---------------------
__global__ __launch_bounds__(256) void convert_all(
    const void* s0, const void* s1, const void* s2, const void* s3,
    const void* s4, const void* s5, const void* s6, const void* s7,
    const void* s8, const void* s9, const void* s10, const void* s11,
    const void* s12, char* __restrict__ ws) {
  const void* srcs[13] = {s0, s1, s2, s3, s4, s5, s6, s7, s8, s9, s10, s11, s12};
  const int counts[13] = {4194304, 4194304, 4194304,
                          1048576, 1024, 1048576, 1024,
                          1048576, 1024, 1048576, 1024,
                          1024, 1024};
  const size_t dofs[13] = {
      0ull, 8ull << 20, 16ull << 20,
      24ull << 20, (32ull << 20) + 0 * 8192, 26ull << 20, (32ull << 20) + 1 * 8192,
      28ull << 20, (32ull << 20) + 2 * 8192, 30ull << 20, (32ull << 20) + 3 * 8192,
      (32ull << 20) + 4 * 8192, (32ull << 20) + 5 * 8192};
  const int bi = blockIdx.y;
  const void* src = srcs[bi];
  bf16x8* dst = (bf16x8*)(ws + dofs[bi]);
  const int nv = counts[bi] >> 3;
  const bool f32 = detect_fp32(src);
  const int idx = blockIdx.x * 256 + threadIdx.x;
  const int stride = gridDim.x * 256;
  if (f32) {
    const float4* s4p = (const float4*)src;
    for (int i = idx; i < nv; i += stride) {
      float4 a = s4p[2 * i], b = s4p[2 * i + 1];
      bf16x8 o;
      o[0] = (bf16_t)a.x; o[1] = (bf16_t)a.y; o[2] = (bf16_t)a.z; o[3] = (bf16_t)a.w;
      o[4] = (bf16_t)b.x; o[5] = (bf16_t)b.y; o[6] = (bf16_t)b.z; o[7] = (bf16_t)b.w;
      dst[i] = o;
    }
  } else {
    const bf16x8* s8p = (const bf16x8*)src;
    for (int i = idx; i < nv; i += stride) dst[i] = s8p[i];
  }
}

// ---- mask pack (row-major): mQb[b][q][k/8 bytes], bit k%8; 1 => drop -------
__device__ __forceinline__ int detect_mask(const uint8_t* p) {
  const uint32_t* w = (const uint32_t*)p;
  bool i32 = true;
  for (int i = 0; i < 32; ++i) i32 &= (w[i] <= 1u);
  if (i32) return 0;
  const uint16_t* hh = (const uint16_t*)p;
  bool evz = true, oddok = true, allbf = true, allf16 = true;
  for (int i = 0; i < 32; ++i) {
    uint16_t e = hh[2 * i], o = hh[2 * i + 1];
    evz &= (e == 0);
    oddok &= (o == 0 || o == 0x3F80);
    allbf &= (e == 0 || e == 0x3F80) && (o == 0 || o == 0x3F80);
    allf16 &= (e == 0 || e == 0x3C00) && (o == 0 || o == 0x3C00);
  }
  if (evz && oddok) return 1;
  if (allbf || allf16) return 2;
  return 3;
}

__global__ __launch_bounds__(256) void mask_pack(const uint8_t* __restrict__ mraw,
                                                 uint8_t* __restrict__ outp) {
  const int mode = detect_mask(mraw);
  const int bq = blockIdx.x;              // b*2048 + q
  const int L = threadIdx.x;              // byte index: keys L*8..L*8+7
  const size_t base = (size_t)bq * 2048 + L * 8;
  uint32_t byte = 0;
  if (mode == 0) {
    const int* m = (const int*)mraw;
    for (int j = 0; j < 8; ++j) byte |= (m[base + j] != 0 ? 1u : 0u) << j;
  } else if (mode == 1) {
    const uint32_t* m = (const uint32_t*)mraw;
    for (int j = 0; j < 8; ++j) byte |= (m[base + j] != 0u ? 1u : 0u) << j;
  } else if (mode == 2) {
    const uint16_t* m = (const uint16_t*)mraw;
    for (int j = 0; j < 8; ++j) byte |= (m[base + j] != 0 ? 1u : 0u) << j;
  } else {
    for (int j = 0; j < 8; ++j) byte |= (mraw[base + j] != 0 ? 1u : 0u) << j;
  }
  outp[(size_t)bq * 256 + L] = (uint8_t)byte;
}

// ---- GEMM core (unchanged) --------------------------------------------------
template <int MODE>
__device__ __forceinline__ void gemm_tile(const bf16_t* __restrict__ X,
                                          const bf16_t* __restrict__ W,
                                          const bf16_t* __restrict__ bias,
                                          const bf16_t* __restrict__ QresB,
                                          const float* __restrict__ QresF,
                                          bool qres_is_f32,
                                          void* __restrict__ outv) {
  __shared__ __align__(16) bf16_t sA[128 * 32];
  __shared__ __align__(16) bf16_t sB[128 * 32];
  const int tm = blockIdx.x * 128;
  const int tn = blockIdx.y * 128;
  const int t = threadIdx.x;
  const int w = t >> 6, l = t & 63, lc = l & 15, ql = l >> 4;
  const int wm = (w >> 1) * 64, wn = (w & 1) * 64;
  f32x4 acc[4][4];
  for (int i = 0; i < 4; ++i)
    for (int j = 0; j < 4; ++j) acc[i][j] = splat4(0.0f);

  const int m0 = t >> 2;
  const int kc0 = (t & 3) * 8;

  for (int k0 = 0; k0 < 1024; k0 += 32) {
    __syncthreads();
    async_copy16((char*)sA + w * 1024,        X + (size_t)(tm + m0) * 1024 + k0 + kc0);
    async_copy16((char*)sA + 4096 + w * 1024, X + (size_t)(tm + 64 + m0) * 1024 + k0 + kc0);
    async_copy16((char*)sB + w * 1024,        W + (size_t)(tn + m0) * 1024 + k0 + kc0);
    async_copy16((char*)sB + 4096 + w * 1024, W + (size_t)(tn + 64 + m0) * 1024 + k0 + kc0);
    __syncthreads();

    bf16x8 af[4], bfr[4];
    for (int i = 0; i < 4; ++i)
      af[i] = *(const bf16x8*)(sA + (wm + i * 16 + lc) * 32 + ql * 8);
    for (int j = 0; j < 4; ++j)
      bfr[j] = *(const bf16x8*)(sB + (wn + j * 16 + lc) * 32 + ql * 8);
    for (int i = 0; i < 4; ++i)
      for (int j = 0; j < 4; ++j)
        acc[i][j] = __builtin_amdgcn_mfma_f32_16x16x32_bf16(af[i], bfr[j], acc[i][j], 0, 0, 0);
  }

  float bvals[4];
  for (int j = 0; j < 4; ++j) bvals[j] = (float)bias[tn + wn + j * 16 + lc];
  for (int i = 0; i < 4; ++i) {
    for (int j = 0; j < 4; ++j) {
      const int col = tn + wn + j * 16 + lc;
      for (int v = 0; v < 4; ++v) {
        const int row = tm + wm + i * 16 + ql * 4 + v;
        float val = acc[i][j][v] + bvals[j];
        if (MODE == 0) {
          ((bf16_t*)outv)[(size_t)row * 1024 + col] = (bf16_t)val;
        } else if (MODE == 1) {
          const int b = row >> 11;
          const int x = (row & 2047) * 1024 + col;
          const int h = x >> 17;
          const int s = (x >> 6) & 2047;
          const int d = x & 63;
          ((bf16_t*)outv)[(size_t)((b * 16 + h) * 64 + d) * 2048 + s] = (bf16_t)val;
        } else {
          val += qres_is_f32 ? QresF[(size_t)row * 1024 + col]
                             : (float)QresB[(size_t)row * 1024 + col];
          ((float*)outv)[(size_t)row * 1024 + col] = val;
        }
      }
    }
  }
}

__global__ __launch_bounds__(256, 2) void qkv_gemm(
    const bf16_t* __restrict__ Q, const bf16_t* __restrict__ K, const bf16_t* __restrict__ V,
    const bf16_t* __restrict__ wq, const bf16_t* __restrict__ bq,
    const bf16_t* __restrict__ wk, const bf16_t* __restrict__ bk,
    const bf16_t* __restrict__ wv, const bf16_t* __restrict__ bv,
    bf16_t* __restrict__ qlin, bf16_t* __restrict__ klin, bf16_t* __restrict__ vT) {
  if (blockIdx.z == 0)      gemm_tile<0>(Q, wq, bq, nullptr, nullptr, false, qlin);
  else if (blockIdx.z == 1) gemm_tile<0>(K, wk, bk, nullptr, nullptr, false, klin);
  else                      gemm_tile<1>(V, wv, bv, nullptr, nullptr, false, vT);
}

__global__ __launch_bounds__(256, 2) void final_gemm(
    const bf16_t* __restrict__ ctx, const bf16_t* __restrict__ wo,
    const bf16_t* __restrict__ bo, const bf16_t* __restrict__ QresB,
    const void* __restrict__ Qraw, float* __restrict__ xres) {
  const bool qf32 = detect_fp32(Qraw);
  gemm_tile<2>(ctx, wo, bo, QresB, (const float*)Qraw, qf32, xres);
}

// ---- flash attention v2: S^T trick, no P round-trip, swizzled LDS ----------
// Block = (b, h, 128-q tile); 4 waves x 32 q; 16 key-tiles of 128.
// S^T = K·Q^T  => C-layout (key=ql*4+v, q=lc) == A-layout of PV MFMA.
// PV uses K=32 MFMA over paired 16-key blocks with shared key permutation
// sigma(ql*8+i) = 32p + (i>=4)*16 + ql*4 + (i&3)  (P·V invariant under any
// key permutation applied to both operands).
__global__ __launch_bounds__(256, 2) void attn(const bf16_t* __restrict__ qlin,
                                               const bf16_t* __restrict__ klin,
                                               const bf16_t* __restrict__ vT,
                                               const uint8_t* __restrict__ mQb,
                                               bf16_t* __restrict__ ctx) {
  // sK: 128 key-rows x 128B, 16B chunks placed at  p = c ^ (row&7)
  // sVt: 64 dv-rows  x 256B, 16B chunks placed at  p = c ^ (row&15)
  __shared__ __align__(16) bf16_t sK[128 * 64];    // 16 KB
  __shared__ __align__(16) bf16_t sVt[64 * 128];   // 16 KB
  __shared__ __align__(16) uint8_t sM[128 * 16];   // 2 KB: [q][16B mask]

  const int t = threadIdx.x, w = t >> 6, l = t & 63, lc = l & 15, ql = l >> 4;
  const int bid = blockIdx.x;
  const int qt = bid & 15, h = (bid >> 4) & 15, b = bid >> 8;
  const int q0 = qt * 128, rb = w * 32;

  const bf16_t* qh = qlin + (size_t)(b * 16 + h) * 2048 * 64;
  const bf16_t* kh = klin + (size_t)(b * 16 + h) * 2048 * 64;
  const bf16_t* vh = vT   + (size_t)(b * 16 + h) * 64 * 2048;
  const uint8_t* mh = mQb + ((size_t)(b * 2048 + q0)) * 256;

  // staging source precompute (swizzle on global side; LDS dest contiguous)
  const int kRow = w * 8 + (l >> 3);                       // + is*32
  const int kChk = (l & 7) ^ ((l >> 3) & 7);
  const int vRow = w * 4 + (l >> 4);                       // + is*16
  const int vChk = (l & 15) ^ (w * 4 + (l >> 4));

  // Q fragments (B-operand of S^T MFMA): rows q0+rb+iq*16+lc
  bf16x8 qf[2][2];
  for (int iq = 0; iq < 2; ++iq)
    for (int c = 0; c < 2; ++c)
      qf[iq][c] = *(const bf16x8*)(qh + (size_t)(q0 + rb + iq * 16 + lc) * 64 + c * 32 + ql * 8);

  float m_st[2] = {-3e38f, -3e38f};
  float l_st[2] = {0.0f, 0.0f};
  f32x4 oacc[2][4];
  for (int iq = 0; iq < 2; ++iq)
    for (int n = 0; n < 4; ++n) oacc[iq][n] = splat4(0.0f);

  const float SCL = 0.18033688f;  // log2(e)/sqrt(64)

  for (int kt = 0; kt < 16; ++kt) {
    const int k0 = kt * 128;
    __syncthreads();
    for (int is = 0; is < 4; ++is)
      async_copy16((char*)sK + is * 4096 + w * 1024,
                   kh + (size_t)(k0 + is * 32 + kRow) * 64 + kChk * 8);
    for (int is = 0; is < 4; ++is)
      async_copy16((char*)sVt + is * 4096 + w * 1024,
                   vh + (size_t)(is * 16 + vRow) * 2048 + k0 + vChk * 8);
    if (w < 2)
      async_copy16((char*)sM + w * 1024, mh + (size_t)(w * 64 + l) * 256 + kt * 16);
    __syncthreads();

    // ---- S^T = K·Q^T:  sc[iq][j] holds S^T[key=j*16+ql*4+v][q=rb+iq*16+lc]
    f32x4 sc[2][8];
    for (int j = 0; j < 8; ++j) {
      const char* kbase = (const char*)sK + (j * 16 + lc) * 128;
      bf16x8 ka0 = *(const bf16x8*)(kbase + ((ql    ) ^ (lc & 7)) * 16);
      bf16x8 ka1 = *(const bf16x8*)(kbase + ((ql + 4) ^ (lc & 7)) * 16);
      sc[0][j] = __builtin_amdgcn_mfma_f32_16x16x32_bf16(ka0, qf[0][0], splat4(0.0f), 0, 0, 0);
      sc[0][j] = __builtin_amdgcn_mfma_f32_16x16x32_bf16(ka1, qf[0][1], sc[0][j], 0, 0, 0);
      sc[1][j] = __builtin_amdgcn_mfma_f32_16x16x32_bf16(ka0, qf[1][0], splat4(0.0f), 0, 0, 0);
      sc[1][j] = __builtin_amdgcn_mfma_f32_16x16x32_bf16(ka1, qf[1][1], sc[1][j], 0, 0, 0);
    }

    // ---- online softmax per q (=lc+16iq+rb), keys spread over (j, ql, v)
    bf16x4 pa[2][8];
    for (int iq = 0; iq < 2; ++iq) {
      const uint4 mq = *(const uint4*)(sM + (rb + iq * 16 + lc) * 16);
      const uint32_t mwarr[4] = {mq.x, mq.y, mq.z, mq.w};

      float rmax = sc[iq][0][0];
      for (int j = 0; j < 8; ++j)
        for (int v = 0; v < 4; ++v) rmax = fmaxf(rmax, sc[iq][j][v]);
      rmax = fmaxf(rmax, __shfl_xor(rmax, 16, 64));
      rmax = fmaxf(rmax, __shfl_xor(rmax, 32, 64));

      const float mnew = fmaxf(m_st[iq], rmax);
      const float alpha = EXP2F((m_st[iq] - mnew) * SCL);
      m_st[iq] = mnew;
      const float nm = mnew * SCL;

      float rsum = 0.0f;
      for (int j = 0; j < 8; ++j) {
        const uint32_t m4 = mwarr[j >> 1] >> (((j & 1) << 4) + (ql << 2));
        bf16x4 pj;
        for (int v = 0; v < 4; ++v) {
          float e = EXP2F(sc[iq][j][v] * SCL - nm);
          e = ((m4 >> v) & 1u) ? 0.0f : e;
          rsum += e;
          pj[v] = (bf16_t)e;
        }
        pa[iq][j] = pj;
      }
      rsum += __shfl_xor(rsum, 16, 64);
      rsum += __shfl_xor(rsum, 32, 64);
      l_st[iq] = l_st[iq] * alpha + rsum;

      // rescale O: gather alpha for this lane's accumulator rows q'=ql*4+v
      f32x4 av;
      for (int v = 0; v < 4; ++v) av[v] = __shfl(alpha, ql * 20 + v, 64);
      for (int n = 0; n < 4; ++n) oacc[iq][n] *= av;
    }

    // ---- O += P·V  (K=32 MFMA over paired blocks; A straight from regs)
    for (int p = 0; p < 4; ++p) {
      bf16x8 a0, a1;
      for (int v = 0; v < 4; ++v) {
        a0[v] = pa[0][2 * p][v]; a0[4 + v] = pa[0][2 * p + 1][v];
        a1[v] = pa[1][2 * p][v]; a1[4 + v] = pa[1][2 * p + 1][v];
      }
      for (int n = 0; n < 4; ++n) {
        const char* vrow = (const char*)sVt + (n * 16 + lc) * 256 + (ql & 1) * 8;
        const bf16x4 v0 = *(const bf16x4*)(vrow + (((4 * p     + (ql >> 1)) ^ lc) * 16));
        const bf16x4 v1 = *(const bf16x4*)(vrow + (((4 * p + 2 + (ql >> 1)) ^ lc) * 16));
        bf16x8 vb;
        for (int v = 0; v < 4; ++v) { vb[v] = v0[v]; vb[4 + v] = v1[v]; }
        oacc[0][n] = __builtin_amdgcn_mfma_f32_16x16x32_bf16(a0, vb, oacc[0][n], 0, 0, 0);
        oacc[1][n] = __builtin_amdgcn_mfma_f32_16x16x32_bf16(a1, vb, oacc[1][n], 0, 0, 0);
      }
    }
  }

  // ---- normalize (gather per-row l) and store ctx[b, s, h*64+dv]
  for (int iq = 0; iq < 2; ++iq) {
    f32x4 linv;
    for (int v = 0; v < 4; ++v) linv[v] = 1.0f / __shfl(l_st[iq], ql * 20 + v, 64);
    for (int n = 0; n < 4; ++n) {
      f32x4 o = oacc[iq][n] * linv;
      for (int v = 0; v < 4; ++v) {
        const int row = q0 + rb + iq * 16 + ql * 4 + v;
        ctx[(size_t)(b * 2048 + row) * 1024 + h * 64 + n * 16 + lc] = (bf16_t)o[v];
      }
    }
  }
}

// ---- LayerNorm (fp32 in/out, in place on d_out) ----------------------------
__global__ __launch_bounds__(256) void ln_k(float* __restrict__ x,
                                            const bf16_t* __restrict__ gamma,
                                            const bf16_t* __restrict__ beta) {
  const int row = blockIdx.x, t = threadIdx.x, w = t >> 6, l = t & 63;
  float* xr = x + (size_t)row * 1024;
  float4 xv = ((const float4*)xr)[t];
  float v0 = xv.x, v1 = xv.y, v2 = xv.z, v3 = xv.w;
  float s1 = v0 + v1 + v2 + v3;
  float s2 = v0 * v0 + v1 * v1 + v2 * v2 + v3 * v3;
  for (int d = 1; d < 64; d <<= 1) {
    s1 += __shfl_xor(s1, d, 64);
    s2 += __shfl_xor(s2, d, 64);
  }
  __shared__ float red[8];
  if (l == 0) { red[w] = s1; red[4 + w] = s2; }
  __syncthreads();
  s1 = red[0] + red[1] + red[2] + red[3];
  s2 = red[4] + red[5] + red[6] + red[7];
  const float mean = s1 * (1.0f / 1024.0f);
  const float var = s2 * (1.0f / 1024.0f) - mean * mean;
  const float rstd = rsqrtf(var + 1e-5f);
  bf16x4 gv = *(const bf16x4*)(gamma + t * 4);
  bf16x4 bv = *(const bf16x4*)(beta + t * 4);
  float4 ov;
  ov.x = (v0 - mean) * rstd * (float)gv[0] + (float)bv[0];
  ov.y = (v1 - mean) * rstd * (float)gv[1] + (float)bv[1];
  ov.z = (v2 - mean) * rstd * (float)gv[2] + (float)bv[2];
  ov.w = (v3 - mean) * rstd * (float)gv[3] + (float)bv[3];
  ((float4*)xr)[t] = ov;
}

// ---- launch ----------------------------------------------------------------
extern "C" void kernel_launch(void* const* d_in, const int* in_sizes, int n_in,
                              void* d_out, int out_size, void* d_ws, size_t ws_size,
                              hipStream_t stream) {
  const uint8_t* msk = (const uint8_t*)d_in[3];

  char* ws = (char*)d_ws;
  bf16_t* Qc   = (bf16_t*)(ws + 0);
  bf16_t* Kc   = (bf16_t*)(ws + (8ull << 20));
  bf16_t* Vc   = (bf16_t*)(ws + (16ull << 20));
  bf16_t* wqc  = (bf16_t*)(ws + (24ull << 20));
  bf16_t* wkc  = (bf16_t*)(ws + (26ull << 20));
  bf16_t* wvc  = (bf16_t*)(ws + (28ull << 20));
  bf16_t* woc  = (bf16_t*)(ws + (30ull << 20));
  bf16_t* bqc  = (bf16_t*)(ws + (32ull << 20) + 0 * 8192);
  bf16_t* bkc  = (bf16_t*)(ws + (32ull << 20) + 1 * 8192);
  bf16_t* bvc  = (bf16_t*)(ws + (32ull << 20) + 2 * 8192);
  bf16_t* boc  = (bf16_t*)(ws + (32ull << 20) + 3 * 8192);
  bf16_t* gc   = (bf16_t*)(ws + (32ull << 20) + 4 * 8192);
  bf16_t* bec  = (bf16_t*)(ws + (32ull << 20) + 5 * 8192);
  uint8_t* mQb = (uint8_t*)(ws + (33ull << 20));
  bf16_t* qlin = (bf16_t*)(ws + (34ull << 20));
  bf16_t* klin = (bf16_t*)(ws + (42ull << 20));
  bf16_t* vT   = (bf16_t*)(ws + (50ull << 20));
  bf16_t* ctx  = Kc;  // Kc dead after qkv_gemm
  float* outF  = (float*)d_out;

  convert_all<<<dim3(512, 13), 256, 0, stream>>>(
      d_in[0], d_in[1], d_in[2], d_in[4], d_in[5], d_in[6], d_in[7],
      d_in[8], d_in[9], d_in[10], d_in[11], d_in[12], d_in[13], ws);
  mask_pack<<<dim3(4096), 256, 0, stream>>>(msk, mQb);
  qkv_gemm<<<dim3(32, 8, 3), 256, 0, stream>>>(Qc, Kc, Vc, wqc, bqc, wkc, bkc,
                                               wvc, bvc, qlin, klin, vT);
  attn<<<dim3(512), 256, 0, stream>>>(qlin, klin, vT, mQb, ctx);
  final_gemm<<<dim3(32, 8), 256, 0, stream>>>(ctx, woc, boc, Qc, d_in[0], outF);
  ln_k<<<dim3(4096), 256, 0, stream>>>(outF, gc, bec);
}